// Round 5
// baseline (91.510 us; speedup 1.0000x reference)
//
#include <hip/hip_runtime.h>

// One-sided Chamfer: for each x_i (N=16384), min_j ||y_j - x_i||^2 over M=16384 y.
// t_ij = ||y_j||^2 - 2 x_i.y_j ; d_i = min_j t_ij + ||x_i||^2 (folded in main).
// Packed-fp32 form: pair x-points in float2 registers so SLP can emit
// v_pk_fma_f32 (2 fmas/lane/instr): per 2 (x,y) pairs = 3 pk_fma + 2 v_min
// -> 2.5 instr-lanes/pair, VALU floor 8.5us (vs 13.7 scalar).
// Grid 4x128 = 512 blocks (2/CU, 2 waves/SIMD); 1 ds_read_b128 broadcast per
// 40 VALU -> DS pipe 5.1us << VALU. Measured total carries ~65us fixed harness
// reset (268MB ws re-poison = ~41us, fillBufferAligned) we cannot affect.

constexpr int TPB = 256;
constexpr int XPAIR = 8;          // 8 float2 pairs = 16 x-points per thread
constexpr int MAX_YCHUNK = 256;   // LDS float4[256] = 4KB

__global__ __launch_bounds__(TPB) void chamfer_main(
    const float* __restrict__ x, const float* __restrict__ y,
    float* __restrict__ part, int N, int M, int ychunk) {
  __shared__ float4 sy[MAX_YCHUNK];
  const int t = threadIdx.x;
  const int bx = blockIdx.x;  // x block (TPB*2*XPAIR x-points)
  const int s = blockIdx.y;   // y chunk index

  // Stage + transform this block's y chunk into LDS.
  for (int jj = t; jj < ychunk; jj += TPB) {
    const int j = s * ychunk + jj;
    if (j < M) {
      const float y0 = y[3 * j], y1 = y[3 * j + 1], y2 = y[3 * j + 2];
      sy[jj] = make_float4(-2.0f * y0, -2.0f * y1, -2.0f * y2,
                           y0 * y0 + y1 * y1 + y2 * y2);
    } else {
      sy[jj] = make_float4(0.0f, 0.0f, 0.0f, __builtin_inff());
    }
  }
  __syncthreads();

  float2 x0[XPAIR], x1[XPAIR], x2[XPAIR], mn[XPAIR], xsq[XPAIR];
  const int base = bx * (TPB * 2 * XPAIR) + 2 * t;
#pragma unroll
  for (int k = 0; k < XPAIR; k++) {
    int i0 = base + k * 2 * TPB;
    int i1 = i0 + 1;
    i0 = (i0 < N) ? i0 : 0;
    i1 = (i1 < N) ? i1 : 0;
    x0[k] = make_float2(x[3 * i0], x[3 * i1]);
    x1[k] = make_float2(x[3 * i0 + 1], x[3 * i1 + 1]);
    x2[k] = make_float2(x[3 * i0 + 2], x[3 * i1 + 2]);
    xsq[k].x = x0[k].x * x0[k].x + x1[k].x * x1[k].x + x2[k].x * x2[k].x;
    xsq[k].y = x0[k].y * x0[k].y + x1[k].y * x1[k].y + x2[k].y * x2[k].y;
    mn[k] = make_float2(__builtin_inff(), __builtin_inff());
  }

#pragma unroll 2
  for (int jj = 0; jj < ychunk; jj++) {
    const float4 q = sy[jj];  // wave-uniform -> LDS broadcast, conflict-free
#pragma unroll
    for (int k = 0; k < XPAIR; k++) {
      float2 acc;  // isomorphic lanes: SLP -> v_pk_fma_f32 (y-scalars splat)
      acc.x = fmaf(x2[k].x, q.z, q.w);
      acc.y = fmaf(x2[k].y, q.z, q.w);
      acc.x = fmaf(x1[k].x, q.y, acc.x);
      acc.y = fmaf(x1[k].y, q.y, acc.y);
      acc.x = fmaf(x0[k].x, q.x, acc.x);
      acc.y = fmaf(x0[k].y, q.x, acc.y);
      mn[k].x = fminf(mn[k].x, acc.x);
      mn[k].y = fminf(mn[k].y, acc.y);
    }
  }

  // Fold ||x||^2 here so the reduce never touches x. Coalesced float2 stores.
  float2* prow = (float2*)(part + (size_t)s * N);
#pragma unroll
  for (int k = 0; k < XPAIR; k++) {
    const int i0 = base + k * 2 * TPB;
    const float2 v = make_float2(mn[k].x + xsq[k].x, mn[k].y + xsq[k].y);
    if (i0 + 1 < N) {
      prow[i0 >> 1] = v;
    } else if (i0 < N) {
      part[(size_t)s * N + i0] = v.x;
    }
  }
}

__global__ __launch_bounds__(64) void chamfer_reduce(
    const float* __restrict__ part, float* __restrict__ out, int N, int S) {
  const int i = blockIdx.x * 64 + threadIdx.x;
  float v = 0.0f;
  if (i < N) {
    float m = __builtin_inff();
#pragma unroll 8
    for (int s = 0; s < S; s++) m = fminf(m, part[(size_t)s * N + i]);
    out[1 + i] = m;
    v = m;
  }
  // Wave-level deterministic sum, then one atomic per wave (256 total).
#pragma unroll
  for (int off = 32; off > 0; off >>= 1) v += __shfl_down(v, off, 64);
  if (threadIdx.x == 0) atomicAdd(out, v);
}

extern "C" void kernel_launch(void* const* d_in, const int* in_sizes, int n_in,
                              void* d_out, int out_size, void* d_ws, size_t ws_size,
                              hipStream_t stream) {
  const float* x = (const float*)d_in[0];
  const float* y = (const float*)d_in[1];
  float* out = (float*)d_out;

  const int N = in_sizes[0] / 3;  // 16384
  const int M = in_sizes[1] / 3;  // 16384

  // y-split count S: partials [S][N] must fit in workspace; ychunk <= MAX_YCHUNK.
  int S = 128;
  while (S > 8 && (size_t)S * N * sizeof(float) > ws_size) S >>= 1;
  const int ychunk = (M + S - 1) / S;  // 128 at S=128

  float* part = (float*)d_ws;  // [S][N]

  // Zero the scalar-sum slot (graph-capturable memset node).
  hipMemsetAsync(out, 0, sizeof(float), stream);

  const int xblocks = (N + TPB * 2 * XPAIR - 1) / (TPB * 2 * XPAIR);  // 4
  dim3 gridB(xblocks, S);                                             // 512 blocks
  chamfer_main<<<gridB, TPB, 0, stream>>>(x, y, part, N, M, ychunk);

  const int rblocks = (N + 63) / 64;  // 256 blocks, 1 wave each
  chamfer_reduce<<<rblocks, 64, 0, stream>>>(part, out, N, S);
}

// Round 6
// 86.317 us; speedup vs baseline: 1.0602x; 1.0602x over previous
//
#include <hip/hip_runtime.h>

// One-sided Chamfer: for each x_i (N=16384), min_j ||y_j - x_i||^2 over M=16384 y.
// t_ij = ||y_j||^2 - 2 x_i.y_j (per-y float4(-2y0,-2y1,-2y2,||y||^2) in LDS);
// d_i = min_j t_ij + ||x_i||^2 (folded here so reduce never reads x).
// fp32 ALU ceiling is 1 fma/lane/cy (157.3 TF) -- packing does NOT help (R4).
// Instruction-count trick: process y in pairs, fminf(fminf(ta,tb),mn) ->
// v_min3_f32, so 2 pairs = 6 fma + 1 min3 = 3.5 instr/pair -> 12.0us floor.
// Grid 8x64 = 512 blocks (2/CU, 2 waves/SIMD); 1 ds_read_b128 broadcast per
// 28 VALU -> LDS pipe 10.2us < VALU bound. Total carries ~63us fixed harness
// reset (268MB ws re-poison @ ~6.5TB/s = ~41us, fillBufferAligned) we cannot
// affect; controllable part is main + reduce + 1 memset node.

constexpr int TPB = 256;         // threads per block
constexpr int XPT = 8;           // x points per thread
constexpr int MAX_YCHUNK = 512;  // LDS: 512 * 16B = 8KB max

__global__ __launch_bounds__(TPB) void chamfer_main(
    const float* __restrict__ x, const float* __restrict__ y,
    float* __restrict__ part, int N, int M, int ychunk) {
  __shared__ float4 sy[MAX_YCHUNK];
  const int t = threadIdx.x;
  const int bx = blockIdx.x;  // x block (TPB*XPT x-points)
  const int s = blockIdx.y;   // y chunk index

  // Stage + transform this block's y chunk into LDS (pad with +inf).
  for (int jj = t; jj < ychunk; jj += TPB) {
    const int j = s * ychunk + jj;
    if (j < M) {
      const float y0 = y[3 * j], y1 = y[3 * j + 1], y2 = y[3 * j + 2];
      sy[jj] = make_float4(-2.0f * y0, -2.0f * y1, -2.0f * y2,
                           y0 * y0 + y1 * y1 + y2 * y2);
    } else {
      sy[jj] = make_float4(0.0f, 0.0f, 0.0f, __builtin_inff());
    }
  }
  __syncthreads();

  float x0[XPT], x1[XPT], x2[XPT], xsq[XPT], mn[XPT];
#pragma unroll
  for (int k = 0; k < XPT; k++) {
    const int i = bx * (TPB * XPT) + k * TPB + t;
    const int ic = (i < N) ? i : 0;
    x0[k] = x[3 * ic];
    x1[k] = x[3 * ic + 1];
    x2[k] = x[3 * ic + 2];
    xsq[k] = x0[k] * x0[k] + x1[k] * x1[k] + x2[k] * x2[k];
    mn[k] = __builtin_inff();
  }

  // ychunk is even (256). Two y-points per iteration -> v_min3_f32.
#pragma unroll 2
  for (int jj = 0; jj < ychunk; jj += 2) {
    const float4 qa = sy[jj];      // wave-uniform -> LDS broadcast, no conflict
    const float4 qb = sy[jj + 1];
#pragma unroll
    for (int k = 0; k < XPT; k++) {
      const float ta = fmaf(x0[k], qa.x, fmaf(x1[k], qa.y, fmaf(x2[k], qa.z, qa.w)));
      const float tb = fmaf(x0[k], qb.x, fmaf(x1[k], qb.y, fmaf(x2[k], qb.z, qb.w)));
      mn[k] = fminf(fminf(ta, tb), mn[k]);  // -> v_min3_f32
    }
  }

  // Fold ||x||^2 here; coalesced stores (stride TPB within each k).
#pragma unroll
  for (int k = 0; k < XPT; k++) {
    const int i = bx * (TPB * XPT) + k * TPB + t;
    if (i < N) part[(size_t)s * N + i] = mn[k] + xsq[k];
  }
}

__global__ __launch_bounds__(64) void chamfer_reduce(
    const float* __restrict__ part, float* __restrict__ out, int N, int S) {
  const int i = blockIdx.x * 64 + threadIdx.x;
  float v = 0.0f;
  if (i < N) {
    float m = __builtin_inff();
#pragma unroll 8
    for (int s = 0; s < S; s++) m = fminf(m, part[(size_t)s * N + i]);
    out[1 + i] = m;
    v = m;
  }
  // Wave-level deterministic sum, then one atomic per wave (256 total;
  // fp ordering jitter << 5.1 abs threshold).
#pragma unroll
  for (int off = 32; off > 0; off >>= 1) v += __shfl_down(v, off, 64);
  if (threadIdx.x == 0) atomicAdd(out, v);
}

extern "C" void kernel_launch(void* const* d_in, const int* in_sizes, int n_in,
                              void* d_out, int out_size, void* d_ws, size_t ws_size,
                              hipStream_t stream) {
  const float* x = (const float*)d_in[0];
  const float* y = (const float*)d_in[1];
  float* out = (float*)d_out;

  const int N = in_sizes[0] / 3;  // 16384
  const int M = in_sizes[1] / 3;  // 16384

  // y-split count S: partials [S][N] must fit in workspace; ychunk <= MAX_YCHUNK.
  int S = 64;
  while (S > 8 && (size_t)S * N * sizeof(float) > ws_size) S >>= 1;
  const int ychunk = (M + S - 1) / S;  // 256 at S=64

  float* part = (float*)d_ws;  // [S][N]

  // Zero the scalar-sum slot (graph-capturable memset node).
  hipMemsetAsync(out, 0, sizeof(float), stream);

  const int xblocks = (N + TPB * XPT - 1) / (TPB * XPT);  // 8
  dim3 gridB(xblocks, S);                                 // 512 blocks
  chamfer_main<<<gridB, TPB, 0, stream>>>(x, y, part, N, M, ychunk);

  const int rblocks = (N + 63) / 64;  // 256 blocks, 1 wave each
  chamfer_reduce<<<rblocks, 64, 0, stream>>>(part, out, N, S);
}